// Round 1
// baseline (743.489 us; speedup 1.0000x reference)
//
#include <hip/hip_runtime.h>
#include <math.h>

#define D 128
#define MT_STRIDE 132   // padded LDS row stride (floats) for transposed M
#define KB 8            // rows per staged batch
#define EPS 1e-6f

__device__ __forceinline__ float elu1(float x) {
    // F.elu(x)+1 with alpha=1: x>0 ? x+1 : exp(x)
    return x > 0.f ? x + 1.f : __expf(x);
}

// ---------------------------------------------------------------------------
// Kernel A: per (bh, chunk) compute partial M_delta = sigma_k^T @ delta_v and
// partial z_sum = sum_s sigma_k, where
//   delta_v = V - (sigma_k @ M) / (sigma_k @ z + eps)
// ---------------------------------------------------------------------------
__global__ __launch_bounds__(256, 2)
void k_update_partial(const float* __restrict__ key,
                      const float* __restrict__ value,
                      const float* __restrict__ M,
                      const float* __restrict__ z,
                      float* __restrict__ pM,   // [BH, NCH, D*D]
                      float* __restrict__ pz,   // [BH, NCH, D]
                      int S)
{
    __shared__ float MT[D * MT_STRIDE];   // MT[e*stride + d] = M[d*D + e]
    __shared__ float zsh[D];
    __shared__ float skb[KB][D];
    __shared__ float dvb[KB][D];
    __shared__ float normsh[KB];

    const int t  = threadIdx.x;
    const int bh = blockIdx.x;
    const int ch = blockIdx.y;
    const int NCH = gridDim.y;
    const int SC = S / NCH;
    const int s_begin = ch * SC;

    const float* Mb = M + (size_t)bh * D * D;
    const float* zb = z + (size_t)bh * D;
    const float* Kb = key   + (size_t)bh * S * D;
    const float* Vb = value + (size_t)bh * S * D;

    // stage M transposed (coalesced global read)
    #pragma unroll
    for (int i = 0; i < (D * D) / 256; ++i) {
        int idx = t + i * 256;
        int d = idx >> 7, e = idx & (D - 1);
        MT[e * MT_STRIDE + d] = Mb[idx];
    }
    if (t < D) zsh[t] = zb[t];
    __syncthreads();

    float acc[8][8];
    #pragma unroll
    for (int i = 0; i < 8; ++i)
        #pragma unroll
        for (int j = 0; j < 8; ++j) acc[i][j] = 0.f;
    float zp = 0.f;

    const int ty = t >> 4;   // 0..15 : d-tile (sigma_k dim)
    const int tx = t & 15;   // 0..15 : e-tile (delta_v dim)

    for (int s0 = s_begin; s0 < s_begin + SC; s0 += KB) {
        // --- stage sigma_k batch ---
        #pragma unroll
        for (int i = 0; i < (KB * D) / 256; ++i) {
            int idx = t + i * 256;
            int r = idx >> 7, c = idx & (D - 1);
            skb[r][c] = elu1(Kb[(size_t)(s0 + r) * D + c]);
        }
        __syncthreads();

        // --- normalizer per row: 8 groups of 32 lanes ---
        {
            int g = t >> 5, l = t & 31;
            float p = 0.f;
            #pragma unroll
            for (int c = 0; c < D; c += 32) p += skb[g][l + c] * zsh[l + c];
            #pragma unroll
            for (int m = 16; m >= 1; m >>= 1) p += __shfl_xor(p, m, 64);
            if (l == 0) normsh[g] = p + EPS;
        }
        __syncthreads();

        // --- mem_pred + delta_v: each thread owns 1 column x 4 rows ---
        {
            int c  = t & (D - 1);
            int rb = (t >> 7) * 4;   // 0 or 4
            float mp[4] = {0.f, 0.f, 0.f, 0.f};
            #pragma unroll
            for (int d = 0; d < D; d += 4) {
                float4 m4 = *(const float4*)&MT[c * MT_STRIDE + d];
                #pragma unroll
                for (int r = 0; r < 4; ++r) {
                    float4 s4 = *(const float4*)&skb[rb + r][d];
                    mp[r] += s4.x * m4.x + s4.y * m4.y + s4.z * m4.z + s4.w * m4.w;
                }
            }
            #pragma unroll
            for (int r = 0; r < 4; ++r) {
                float dv = Vb[(size_t)(s0 + rb + r) * D + c] - mp[r] / normsh[rb + r];
                dvb[rb + r][c] = dv;
            }
        }
        __syncthreads();

        // --- outer-product accumulation: acc[d_tile][e_tile] ---
        #pragma unroll
        for (int k = 0; k < KB; ++k) {
            float4 a0 = *(const float4*)&skb[k][ty * 8];
            float4 a1 = *(const float4*)&skb[k][ty * 8 + 4];
            float4 b0 = *(const float4*)&dvb[k][tx * 8];
            float4 b1 = *(const float4*)&dvb[k][tx * 8 + 4];
            float a[8] = {a0.x, a0.y, a0.z, a0.w, a1.x, a1.y, a1.z, a1.w};
            float b[8] = {b0.x, b0.y, b0.z, b0.w, b1.x, b1.y, b1.z, b1.w};
            #pragma unroll
            for (int i = 0; i < 8; ++i)
                #pragma unroll
                for (int j = 0; j < 8; ++j)
                    acc[i][j] = fmaf(a[i], b[j], acc[i][j]);
        }
        // z partial (sum of sigma_k over rows)
        if (t < D) {
            #pragma unroll
            for (int k = 0; k < KB; ++k) zp += skb[k][t];
        }
        __syncthreads();
    }

    // write partials
    float* pMb = pM + ((size_t)bh * NCH + ch) * (D * D);
    #pragma unroll
    for (int i = 0; i < 8; ++i)
        #pragma unroll
        for (int j = 0; j < 8; ++j)
            pMb[(ty * 8 + i) * D + (tx * 8 + j)] = acc[i][j];
    if (t < D) pz[((size_t)bh * NCH + ch) * D + t] = zp;
}

// ---------------------------------------------------------------------------
// Kernel B: M_new = M + sum_ch pM ; z_new = z + sum_ch pz
// (works in-place when pM==Mnew, pz==znew with NCH==1)
// ---------------------------------------------------------------------------
__global__ void k_reduce(const float* __restrict__ M,
                         const float* __restrict__ z,
                         const float* __restrict__ pM,
                         const float* __restrict__ pz,
                         float* __restrict__ Mnew,
                         float* __restrict__ znew,
                         int NCH)
{
    const int bh = blockIdx.x;
    const int t  = threadIdx.x;
    const size_t baseM = (size_t)bh * D * D;
    for (int i = t; i < D * D; i += 256) {
        float acc = M[baseM + i];
        for (int c = 0; c < NCH; ++c)
            acc += pM[((size_t)bh * NCH + c) * (D * D) + i];
        Mnew[baseM + i] = acc;
    }
    if (t < D) {
        float acc = z[(size_t)bh * D + t];
        for (int c = 0; c < NCH; ++c)
            acc += pz[((size_t)bh * NCH + c) * D + t];
        znew[(size_t)bh * D + t] = acc;
    }
}

// ---------------------------------------------------------------------------
// Kernel C: out = (sigma_q @ M_new) / (sigma_q @ z_new + eps)
// ---------------------------------------------------------------------------
__global__ __launch_bounds__(256, 2)
void k_retrieve(const float* __restrict__ query,
                const float* __restrict__ Mnew,
                const float* __restrict__ znew,
                float* __restrict__ out,
                int S)
{
    __shared__ float MT[D * MT_STRIDE];
    __shared__ float zsh[D];
    __shared__ float sqb[KB][D];
    __shared__ float normsh[KB];

    const int t  = threadIdx.x;
    const int bh = blockIdx.x;
    const int ch = blockIdx.y;
    const int NCH = gridDim.y;
    const int SC = S / NCH;
    const int s_begin = ch * SC;

    const float* Mb = Mnew + (size_t)bh * D * D;
    const float* zb = znew + (size_t)bh * D;
    const float* Qb = query + (size_t)bh * S * D;
    float*       Ob = out   + (size_t)bh * S * D;

    #pragma unroll
    for (int i = 0; i < (D * D) / 256; ++i) {
        int idx = t + i * 256;
        int d = idx >> 7, e = idx & (D - 1);
        MT[e * MT_STRIDE + d] = Mb[idx];
    }
    if (t < D) zsh[t] = zb[t];
    __syncthreads();

    for (int s0 = s_begin; s0 < s_begin + SC; s0 += KB) {
        #pragma unroll
        for (int i = 0; i < (KB * D) / 256; ++i) {
            int idx = t + i * 256;
            int r = idx >> 7, c = idx & (D - 1);
            sqb[r][c] = elu1(Qb[(size_t)(s0 + r) * D + c]);
        }
        __syncthreads();

        {
            int g = t >> 5, l = t & 31;
            float p = 0.f;
            #pragma unroll
            for (int c = 0; c < D; c += 32) p += sqb[g][l + c] * zsh[l + c];
            #pragma unroll
            for (int m = 16; m >= 1; m >>= 1) p += __shfl_xor(p, m, 64);
            if (l == 0) normsh[g] = p + EPS;
        }
        __syncthreads();

        {
            int c  = t & (D - 1);
            int rb = (t >> 7) * 4;
            float mp[4] = {0.f, 0.f, 0.f, 0.f};
            #pragma unroll
            for (int d = 0; d < D; d += 4) {
                float4 m4 = *(const float4*)&MT[c * MT_STRIDE + d];
                #pragma unroll
                for (int r = 0; r < 4; ++r) {
                    float4 s4 = *(const float4*)&sqb[rb + r][d];
                    mp[r] += s4.x * m4.x + s4.y * m4.y + s4.z * m4.z + s4.w * m4.w;
                }
            }
            #pragma unroll
            for (int r = 0; r < 4; ++r)
                Ob[(size_t)(s0 + rb + r) * D + c] = mp[r] / normsh[rb + r];
        }
        __syncthreads();
    }
}

// ---------------------------------------------------------------------------
extern "C" void kernel_launch(void* const* d_in, const int* in_sizes, int n_in,
                              void* d_out, int out_size, void* d_ws, size_t ws_size,
                              hipStream_t stream)
{
    const float* q = (const float*)d_in[0];
    const float* k = (const float*)d_in[1];
    const float* v = (const float*)d_in[2];
    const float* M = (const float*)d_in[3];
    const float* z = (const float*)d_in[4];

    const int BH = in_sizes[3] / (D * D);   // 64
    const int S  = in_sizes[0] / (BH * D);  // 4096

    float* out  = (float*)d_out;
    float* Mnew = out + (size_t)BH * S * D;
    float* znew = Mnew + (size_t)BH * D * D;

    // pick largest chunk count whose partials fit in the workspace
    int NCH = 8;
    const size_t per_set = (size_t)BH * (D * D + D) * sizeof(float);
    while (NCH > 1 && (size_t)NCH * per_set > ws_size) NCH >>= 1;

    float* pM;
    float* pz;
    if ((size_t)NCH * per_set <= ws_size) {
        pM = (float*)d_ws;
        pz = pM + (size_t)NCH * BH * D * D;
    } else {
        // no usable workspace: single chunk, stage partial directly in output
        NCH = 1;
        pM = Mnew;
        pz = znew;
    }

    dim3 gridA(BH, NCH);
    k_update_partial<<<gridA, 256, 0, stream>>>(k, v, M, z, pM, pz, S);
    k_reduce<<<BH, 256, 0, stream>>>(M, z, pM, pz, Mnew, znew, NCH);
    dim3 gridC(BH, 8);
    k_retrieve<<<gridC, 256, 0, stream>>>(q, Mnew, znew, out, S);
}

// Round 2
// 155.618 us; speedup vs baseline: 4.7777x; 4.7777x over previous
//
#include <hip/hip_runtime.h>
#include <math.h>

#define D 128
#define EPS 1e-6f
#define SKR_LD 136   // shorts per row for row-major sigma tiles (32 rows)
#define SKT_LD 40    // shorts per row for transposed sigma (128 rows)

typedef __attribute__((ext_vector_type(8))) short short8;
typedef __attribute__((ext_vector_type(4))) float f32x4;
typedef unsigned short ushort_t;
typedef unsigned long long u64;

__device__ __forceinline__ float elu1(float x) {
    float e = __expf(fminf(x, 0.f));
    return x > 0.f ? x + 1.f : e;
}
__device__ __forceinline__ unsigned short bf16rne(float f) {
    unsigned u = __builtin_bit_cast(unsigned, f);
    u += 0x7FFFu + ((u >> 16) & 1u);
    return (unsigned short)(u >> 16);
}
__device__ __forceinline__ u64 pack4(float a, float b, float c, float d) {
    return (u64)bf16rne(a) | ((u64)bf16rne(b) << 16) |
           ((u64)bf16rne(c) << 32) | ((u64)bf16rne(d) << 48);
}

// ---------------------------------------------------------------------------
// Update: per (bh, chunk): pM = sigma_k^T @ (V - (sigma_k@M)/(sigma_k@z+eps)),
// pz = sum_s sigma_k.  bf16 MFMA, fp32 accumulate.
// Thread roles: stage (sb = t>>5, db = t&31) handles 4x4 block of the 32x128
// tile; compute (w = t>>6, g = (t>>4)&3, m = t&15), wave w owns e-tiles
// {2w, 2w+1}.
// ---------------------------------------------------------------------------
__global__ __launch_bounds__(256, 2)
void k_update(const float* __restrict__ key, const float* __restrict__ value,
              const float* __restrict__ M, const float* __restrict__ z,
              float* __restrict__ pM, float* __restrict__ pz, int S)
{
    __shared__ alignas(16) ushort_t skR[2][32 * SKR_LD];
    __shared__ alignas(16) ushort_t skT[2][128 * SKT_LD];
    __shared__ float normsh[2][32];
    __shared__ float zsc[8][128];

    const int t  = threadIdx.x;
    const int bh = blockIdx.x, ch = blockIdx.y, NCH = gridDim.y;
    const int SC = S / NCH;
    const int NB = SC / 32;
    const int s0g = ch * SC;

    const int w = t >> 6, g = (t >> 4) & 3, m = t & 15;
    const int sb = t >> 5, db = t & 31;

    const float* Kb = key   + (size_t)bh * S * D;
    const float* Vb = value + (size_t)bh * S * D;
    const float* Mb = M + (size_t)bh * D * D;
    const float* zb = z + (size_t)bh * D;

    float zr[4];
    #pragma unroll
    for (int j = 0; j < 4; ++j) zr[j] = zb[4 * db + j];

    // M B-frags in registers (loop-invariant): Bf[ks][p][j] = M[32ks+8g+j][16(2w+p)+m]
    short8 Bf[4][2];
    #pragma unroll
    for (int ks = 0; ks < 4; ++ks)
        #pragma unroll
        for (int p = 0; p < 2; ++p) {
            short8 f;
            #pragma unroll
            for (int j = 0; j < 8; ++j)
                f[j] = (short)bf16rne(Mb[(size_t)(32 * ks + 8 * g + j) * D + 16 * (2 * w + p) + m]);
            Bf[ks][p] = f;
        }

    f32x4 acc[8][2];
    #pragma unroll
    for (int dt = 0; dt < 8; ++dt)
        #pragma unroll
        for (int p = 0; p < 2; ++p) acc[dt][p] = 0.f;
    float zp[4] = {0.f, 0.f, 0.f, 0.f};

    // stage-process: elu, LDS writes (row-major + transposed), norm, z-sum
    auto STAGE_PROC = [&](const float4* kreg, int bu) {
        float sv[4][4];
        #pragma unroll
        for (int js = 0; js < 4; ++js) {
            sv[js][0] = elu1(kreg[js].x); sv[js][1] = elu1(kreg[js].y);
            sv[js][2] = elu1(kreg[js].z); sv[js][3] = elu1(kreg[js].w);
        }
        #pragma unroll
        for (int js = 0; js < 4; ++js)
            *(u64*)&skR[bu][(4 * sb + js) * SKR_LD + 4 * db] =
                pack4(sv[js][0], sv[js][1], sv[js][2], sv[js][3]);
        #pragma unroll
        for (int jd = 0; jd < 4; ++jd)
            *(u64*)&skT[bu][(4 * db + jd) * SKT_LD + 4 * sb] =
                pack4(sv[0][jd], sv[1][jd], sv[2][jd], sv[3][jd]);
        float np[4];
        #pragma unroll
        for (int js = 0; js < 4; ++js) {
            np[js] = sv[js][0] * zr[0] + sv[js][1] * zr[1] +
                     sv[js][2] * zr[2] + sv[js][3] * zr[3];
            #pragma unroll
            for (int jd = 0; jd < 4; ++jd) zp[jd] += sv[js][jd];
        }
        #pragma unroll
        for (int mask = 16; mask >= 1; mask >>= 1) {
            np[0] += __shfl_xor(np[0], mask, 64);
            np[1] += __shfl_xor(np[1], mask, 64);
            np[2] += __shfl_xor(np[2], mask, 64);
            np[3] += __shfl_xor(np[3], mask, 64);
        }
        if (db < 4) {
            float v = db == 0 ? np[0] : db == 1 ? np[1] : db == 2 ? np[2] : np[3];
            normsh[bu][4 * sb + db] = v + EPS;
        }
    };

    // prologue: stage batch 0
    {
        float4 kreg[4];
        #pragma unroll
        for (int js = 0; js < 4; ++js)
            kreg[js] = *(const float4*)&Kb[(size_t)(s0g + 4 * sb + js) * D + 4 * db];
        STAGE_PROC(kreg, 0);
    }
    __syncthreads();

    for (int b = 0; b < NB; ++b) {
        const int bu = b & 1;
        // prefetch V(b) and K(b+1)
        float vv[2][2][4];
        #pragma unroll
        for (int st = 0; st < 2; ++st)
            #pragma unroll
            for (int p = 0; p < 2; ++p)
                #pragma unroll
                for (int r = 0; r < 4; ++r)
                    vv[st][p][r] = Vb[(size_t)(s0g + 32 * b + 16 * st + 4 * g + r) * D +
                                      16 * (2 * w + p) + m];
        float4 kreg[4];
        if (b + 1 < NB) {
            #pragma unroll
            for (int js = 0; js < 4; ++js)
                kreg[js] = *(const float4*)&Kb[(size_t)(s0g + 32 * (b + 1) + 4 * sb + js) * D + 4 * db];
        }

        // mem_pred = sigma_k @ M
        f32x4 mp[2][2];
        #pragma unroll
        for (int st = 0; st < 2; ++st)
            #pragma unroll
            for (int p = 0; p < 2; ++p) mp[st][p] = 0.f;
        #pragma unroll
        for (int st = 0; st < 2; ++st)
            #pragma unroll
            for (int ks = 0; ks < 4; ++ks) {
                short8 a = *(short8*)&skR[bu][(16 * st + m) * SKR_LD + 32 * ks + 8 * g];
                #pragma unroll
                for (int p = 0; p < 2; ++p)
                    mp[st][p] = __builtin_amdgcn_mfma_f32_16x16x32_bf16(a, Bf[ks][p], mp[st][p], 0, 0, 0);
            }

        // delta_v (fp32)
        float dvv[2][2][4];
        #pragma unroll
        for (int st = 0; st < 2; ++st)
            #pragma unroll
            for (int r = 0; r < 4; ++r) {
                float nrm = normsh[bu][16 * st + 4 * g + r];
                #pragma unroll
                for (int p = 0; p < 2; ++p)
                    dvv[st][p][r] = vv[st][p][r] - mp[st][p][r] / nrm;
            }

        // build delta_v B-frags in-wave via shuffles:
        // B[k=8g+j][n=m] lives in lane ((2g+(j>>2))&3)*16+m, tile st=g>>1, reg j&3
        short8 bfr[2];
        #pragma unroll
        for (int p = 0; p < 2; ++p) {
            short8 f;
            #pragma unroll
            for (int j = 0; j < 8; ++j) {
                int src = ((2 * g + (j >> 2)) & 3) * 16 + m;
                float v0 = __shfl(dvv[0][p][j & 3], src, 64);
                float v1 = __shfl(dvv[1][p][j & 3], src, 64);
                f[j] = (short)bf16rne(g < 2 ? v0 : v1);
            }
            bfr[p] = f;
        }

        // pM += sigma_k^T @ delta_v
        #pragma unroll
        for (int dt = 0; dt < 8; ++dt) {
            short8 a = *(short8*)&skT[bu][(16 * dt + m) * SKT_LD + 8 * g];
            #pragma unroll
            for (int p = 0; p < 2; ++p)
                acc[dt][p] = __builtin_amdgcn_mfma_f32_16x16x32_bf16(a, bfr[p], acc[dt][p], 0, 0, 0);
        }

        if (b + 1 < NB) STAGE_PROC(kreg, (b + 1) & 1);
        __syncthreads();
    }

    // write partials
    float* pMb = pM + ((size_t)bh * NCH + ch) * (D * D);
    #pragma unroll
    for (int dt = 0; dt < 8; ++dt)
        #pragma unroll
        for (int p = 0; p < 2; ++p)
            #pragma unroll
            for (int r = 0; r < 4; ++r)
                pMb[(size_t)(16 * dt + 4 * g + r) * D + 16 * (2 * w + p) + m] = acc[dt][p][r];

    #pragma unroll
    for (int jd = 0; jd < 4; ++jd) zsc[sb][4 * db + jd] = zp[jd];
    __syncthreads();
    if (t < 128) {
        float a = 0.f;
        #pragma unroll
        for (int q = 0; q < 8; ++q) a += zsc[q][t];
        pz[((size_t)bh * NCH + ch) * D + t] = a;
    }
}

// ---------------------------------------------------------------------------
// Reduce: M_new = M + sum_ch pM ; z_new = z + sum_ch pz
// ---------------------------------------------------------------------------
__global__ void k_reduce(const float* __restrict__ M, const float* __restrict__ z,
                         const float* __restrict__ pM, const float* __restrict__ pz,
                         float* __restrict__ Mnew, float* __restrict__ znew, int NCH)
{
    const int bh = blockIdx.x, sl = blockIdx.y, t = threadIdx.x;
    const size_t baseM = (size_t)bh * D * D;
    for (int i = sl * 2048 + t; i < (sl + 1) * 2048; i += 256) {
        float a = M[baseM + i];
        for (int c = 0; c < NCH; ++c) a += pM[((size_t)bh * NCH + c) * (D * D) + i];
        Mnew[baseM + i] = a;
    }
    if (sl == 0 && t < D) {
        float a = z[(size_t)bh * D + t];
        for (int c = 0; c < NCH; ++c) a += pz[((size_t)bh * NCH + c) * D + t];
        znew[(size_t)bh * D + t] = a;
    }
}

// ---------------------------------------------------------------------------
// Retrieve: out = (sigma_q @ M_new) / (sigma_q @ z_new + eps)
// ---------------------------------------------------------------------------
__global__ __launch_bounds__(256, 2)
void k_retrieve(const float* __restrict__ query, const float* __restrict__ Mnew,
                const float* __restrict__ znew, float* __restrict__ out, int S)
{
    __shared__ alignas(16) ushort_t sqR[2][32 * SKR_LD];
    __shared__ float normsh[2][32];

    const int t  = threadIdx.x;
    const int bh = blockIdx.x, ch = blockIdx.y, NCH = gridDim.y;
    const int SC = S / NCH;
    const int NB = SC / 32;
    const int s0g = ch * SC;

    const int w = t >> 6, g = (t >> 4) & 3, m = t & 15;
    const int sb = t >> 5, db = t & 31;

    const float* Qb = query + (size_t)bh * S * D;
    const float* Mb = Mnew + (size_t)bh * D * D;
    const float* zb = znew + (size_t)bh * D;
    float*       Ob = out + (size_t)bh * S * D;

    float zr[4];
    #pragma unroll
    for (int j = 0; j < 4; ++j) zr[j] = zb[4 * db + j];

    short8 Bf[4][2];
    #pragma unroll
    for (int ks = 0; ks < 4; ++ks)
        #pragma unroll
        for (int p = 0; p < 2; ++p) {
            short8 f;
            #pragma unroll
            for (int j = 0; j < 8; ++j)
                f[j] = (short)bf16rne(Mb[(size_t)(32 * ks + 8 * g + j) * D + 16 * (2 * w + p) + m]);
            Bf[ks][p] = f;
        }

    auto STAGE_PROC = [&](const float4* qreg, int bu) {
        float sv[4][4];
        #pragma unroll
        for (int js = 0; js < 4; ++js) {
            sv[js][0] = elu1(qreg[js].x); sv[js][1] = elu1(qreg[js].y);
            sv[js][2] = elu1(qreg[js].z); sv[js][3] = elu1(qreg[js].w);
        }
        #pragma unroll
        for (int js = 0; js < 4; ++js)
            *(u64*)&sqR[bu][(4 * sb + js) * SKR_LD + 4 * db] =
                pack4(sv[js][0], sv[js][1], sv[js][2], sv[js][3]);
        float np[4];
        #pragma unroll
        for (int js = 0; js < 4; ++js)
            np[js] = sv[js][0] * zr[0] + sv[js][1] * zr[1] +
                     sv[js][2] * zr[2] + sv[js][3] * zr[3];
        #pragma unroll
        for (int mask = 16; mask >= 1; mask >>= 1) {
            np[0] += __shfl_xor(np[0], mask, 64);
            np[1] += __shfl_xor(np[1], mask, 64);
            np[2] += __shfl_xor(np[2], mask, 64);
            np[3] += __shfl_xor(np[3], mask, 64);
        }
        if (db < 4) {
            float v = db == 0 ? np[0] : db == 1 ? np[1] : db == 2 ? np[2] : np[3];
            normsh[bu][4 * sb + db] = v + EPS;
        }
    };

    {
        float4 qreg[4];
        #pragma unroll
        for (int js = 0; js < 4; ++js)
            qreg[js] = *(const float4*)&Qb[(size_t)(s0g + 4 * sb + js) * D + 4 * db];
        STAGE_PROC(qreg, 0);
    }
    __syncthreads();

    for (int b = 0; b < NB; ++b) {
        const int bu = b & 1;
        float4 qreg[4];
        if (b + 1 < NB) {
            #pragma unroll
            for (int js = 0; js < 4; ++js)
                qreg[js] = *(const float4*)&Qb[(size_t)(s0g + 32 * (b + 1) + 4 * sb + js) * D + 4 * db];
        }

        f32x4 mp[2][2];
        #pragma unroll
        for (int st = 0; st < 2; ++st)
            #pragma unroll
            for (int p = 0; p < 2; ++p) mp[st][p] = 0.f;
        #pragma unroll
        for (int st = 0; st < 2; ++st)
            #pragma unroll
            for (int ks = 0; ks < 4; ++ks) {
                short8 a = *(short8*)&sqR[bu][(16 * st + m) * SKR_LD + 32 * ks + 8 * g];
                #pragma unroll
                for (int p = 0; p < 2; ++p)
                    mp[st][p] = __builtin_amdgcn_mfma_f32_16x16x32_bf16(a, Bf[ks][p], mp[st][p], 0, 0, 0);
            }

        #pragma unroll
        for (int st = 0; st < 2; ++st)
            #pragma unroll
            for (int r = 0; r < 4; ++r) {
                float rn = 1.f / normsh[bu][16 * st + 4 * g + r];
                #pragma unroll
                for (int p = 0; p < 2; ++p)
                    Ob[(size_t)(s0g + 32 * b + 16 * st + 4 * g + r) * D + 16 * (2 * w + p) + m] =
                        mp[st][p][r] * rn;
            }

        if (b + 1 < NB) STAGE_PROC(qreg, (b + 1) & 1);
        __syncthreads();
    }
}

// ---------------------------------------------------------------------------
extern "C" void kernel_launch(void* const* d_in, const int* in_sizes, int n_in,
                              void* d_out, int out_size, void* d_ws, size_t ws_size,
                              hipStream_t stream)
{
    const float* q = (const float*)d_in[0];
    const float* k = (const float*)d_in[1];
    const float* v = (const float*)d_in[2];
    const float* M = (const float*)d_in[3];
    const float* z = (const float*)d_in[4];

    const int BH = in_sizes[3] / (D * D);
    const int S  = in_sizes[0] / (BH * D);

    float* out  = (float*)d_out;
    float* Mnew = out + (size_t)BH * S * D;
    float* znew = Mnew + (size_t)BH * D * D;

    int NCH = 8;
    const size_t per_set = (size_t)BH * (D * D + D) * sizeof(float);
    while (NCH > 1 && (size_t)NCH * per_set > ws_size) NCH >>= 1;

    float* pM;
    float* pz;
    if ((size_t)NCH * per_set <= ws_size) {
        pM = (float*)d_ws;
        pz = pM + (size_t)NCH * BH * D * D;
    } else {
        NCH = 1;
        pM = Mnew;
        pz = znew;
    }

    dim3 gridA(BH, NCH);
    k_update<<<gridA, 256, 0, stream>>>(k, v, M, z, pM, pz, S);
    dim3 gridB(BH, 8);
    k_reduce<<<gridB, 256, 0, stream>>>(M, z, pM, pz, Mnew, znew, NCH);
    dim3 gridC(BH, 8);
    k_retrieve<<<gridC, 256, 0, stream>>>(q, Mnew, znew, out, S);
}